// Round 20
// baseline (271.780 us; speedup 1.0000x reference)
//
#include <hip/hip_runtime.h>

#define KF 128
#define NSUP 256
#define NSPEC 4
#define BLOCK 256

typedef __bf16 bf16x8 __attribute__((ext_vector_type(8)));
typedef float  f32x4  __attribute__((ext_vector_type(4)));

// ---------------- species bucketing ----------------

__global__ void k_count(const int* __restrict__ sp, int n, int* __restrict__ counts) {
    __shared__ int h[NSPEC];
    if (threadIdx.x < NSPEC) h[threadIdx.x] = 0;
    __syncthreads();
    for (int i = blockIdx.x * blockDim.x + threadIdx.x; i < n; i += gridDim.x * blockDim.x)
        atomicAdd(&h[sp[i]], 1);
    __syncthreads();
    if (threadIdx.x < NSPEC) atomicAdd(&counts[threadIdx.x], h[threadIdx.x]);
}

// dest[i] = position of atom i in species-sorted order (4 monotone streams)
__global__ void k_dest(const int* __restrict__ sp, int n,
                       const int* __restrict__ counts, int* __restrict__ cursors,
                       int* __restrict__ dest) {
    __shared__ int lh[NSPEC];
    __shared__ int basep[NSPEC];
    if (threadIdx.x < NSPEC) lh[threadIdx.x] = 0;
    __syncthreads();
    int i = blockIdx.x * blockDim.x + threadIdx.x;
    int s = (i < n) ? sp[i] : -1;
    int local = 0;
    if (s >= 0) local = atomicAdd(&lh[s], 1);
    __syncthreads();
    if (threadIdx.x < NSPEC) {
        int q = threadIdx.x;
        int off = 0;
        for (int u = 0; u < q; ++u) off += counts[u];
        basep[q] = off + atomicAdd(&cursors[q], lh[q]);
    }
    __syncthreads();
    if (s >= 0) dest[i] = basep[s] + local;
}

// ---------------- build per-species Gram matrix, sigma-permuted fragment-major ----------------
// G[s][c][k] = sum_m w[s][m]*sup[s][m][c]*sup[s][m][k]  (fp32 accum -> bf16)
// t = ((s*8+ct)*4+kk)*64+lane holds G[s][sigma(ct,lane&15)][kk*32+(lane>>4)*8+u], u=0..7
// sigma(ct,i) = (ct>>1)*32 + (i>>2)*8 + (ct&1)*4 + (i&3): MFMA D-layout lands z[c] on
// the lane that already holds x[c] -> pairing needs no cross-lane moves.

__global__ void k_buildG(const float* __restrict__ sup, const float* __restrict__ w,
                         __bf16* __restrict__ gfrag) {
    const int t = blockIdx.x * blockDim.x + threadIdx.x;   // 8192 total
    if (t >= NSPEC * 8 * 4 * 64) return;
    const int lane = t & 63;
    const int kk   = (t >> 6) & 3;
    const int ct   = (t >> 8) & 7;
    const int s    = t >> 11;
    const int i    = lane & 15;
    const int c    = (ct >> 1) * 32 + (i >> 2) * 8 + (ct & 1) * 4 + (i & 3);
    const int k0   = kk * 32 + (lane >> 4) * 8;
    const float* S = sup + (size_t)s * NSUP * KF;
    const float* W = w + s * NSUP;
    float a0 = 0.f, a1 = 0.f, a2 = 0.f, a3 = 0.f, a4 = 0.f, a5 = 0.f, a6 = 0.f, a7 = 0.f;
    for (int m = 0; m < NSUP; ++m) {
        const float wc = W[m] * S[m * KF + c];
        const float4 ka = *(const float4*)(S + m * KF + k0);
        const float4 kb = *(const float4*)(S + m * KF + k0 + 4);
        a0 += wc * ka.x; a1 += wc * ka.y; a2 += wc * ka.z; a3 += wc * ka.w;
        a4 += wc * kb.x; a5 += wc * kb.y; a6 += wc * kb.z; a7 += wc * kb.w;
    }
    bf16x8 o;
    o[0] = (__bf16)a0; o[1] = (__bf16)a1; o[2] = (__bf16)a2; o[3] = (__bf16)a3;
    o[4] = (__bf16)a4; o[5] = (__bf16)a5; o[6] = (__bf16)a6; o[7] = (__bf16)a7;
    *(bf16x8*)(gfrag + (size_t)t * 8) = o;
}

// ---------------- permute: sequential read, species-sorted write, normalize + bf16 ----------------
// 16 lanes per atom. Read ps[i] (coalesced), norm via 4 shfl, scale by rsqrt,
// write 256B bf16 row to psrt[dest[i]] (4 monotone streams -> DRAM-friendly).

__global__ __launch_bounds__(BLOCK, 1) void k_permute(
    const float* __restrict__ ps, const int* __restrict__ dest,
    const int* __restrict__ sids,
    __bf16* __restrict__ psrt, int* __restrict__ sid_s, int n)
{
    const int l16 = threadIdx.x & 15;
    int grp = (blockIdx.x * BLOCK + threadIdx.x) >> 4;
    const int gst = (gridDim.x * BLOCK) >> 4;
    for (int i = grp; i < n; i += gst) {
        const float* p = ps + (size_t)i * KF + l16 * 8;
        float4 a = *(const float4*)(p);
        float4 b = *(const float4*)(p + 4);
        float nn = a.x*a.x + a.y*a.y + a.z*a.z + a.w*a.w
                 + b.x*b.x + b.y*b.y + b.z*b.z + b.w*b.w;
        nn += __shfl_xor(nn, 1); nn += __shfl_xor(nn, 2);
        nn += __shfl_xor(nn, 4); nn += __shfl_xor(nn, 8);
        const float inv = (nn > 0.f) ? rsqrtf(nn) : 0.f;
        bf16x8 o;
        o[0] = (__bf16)(a.x * inv); o[1] = (__bf16)(a.y * inv);
        o[2] = (__bf16)(a.z * inv); o[3] = (__bf16)(a.w * inv);
        o[4] = (__bf16)(b.x * inv); o[5] = (__bf16)(b.y * inv);
        o[6] = (__bf16)(b.z * inv); o[7] = (__bf16)(b.w * inv);
        const int d = dest[i];
        *(bf16x8*)(psrt + (size_t)d * KF + l16 * 8) = o;
        if (l16 == 0) sid_s[d] = sids[i];
    }
}

// ---------------- main: species-pure blocks, 32 KB LDS G, sequential psrt stream ----------------

// One ct-step: 4 G-fragment LDS reads, 4 chained MFMA, pair acc[j] with own-lane
// x-hat from fragment XF ((CT&1)*4 .. +3).  e accumulates x^T G x (already normalized).
#define GSTEP(CT, XF)                                                           \
    {                                                                           \
        const __bf16* gq = gp + (CT) * 2048;                                    \
        f32x4 acc = (f32x4){0.f, 0.f, 0.f, 0.f};                                \
        acc = __builtin_amdgcn_mfma_f32_16x16x32_bf16(                          \
            *(const bf16x8*)(gq), xc0, acc, 0, 0, 0);                           \
        acc = __builtin_amdgcn_mfma_f32_16x16x32_bf16(                          \
            *(const bf16x8*)(gq + 512), xc1, acc, 0, 0, 0);                     \
        acc = __builtin_amdgcn_mfma_f32_16x16x32_bf16(                          \
            *(const bf16x8*)(gq + 1024), xc2, acc, 0, 0, 0);                    \
        acc = __builtin_amdgcn_mfma_f32_16x16x32_bf16(                          \
            *(const bf16x8*)(gq + 1536), xc3, acc, 0, 0, 0);                    \
        es += acc[0] * (float)XF[((CT) & 1) * 4 + 0]                            \
            + acc[1] * (float)XF[((CT) & 1) * 4 + 1]                            \
            + acc[2] * (float)XF[((CT) & 1) * 4 + 2]                            \
            + acc[3] * (float)XF[((CT) & 1) * 4 + 3];                           \
    }

__global__ __launch_bounds__(BLOCK, 1) void k_main(
    const __bf16* __restrict__ psrt,
    const __bf16* __restrict__ gfrag,
    const int* __restrict__ counts,
    const int* __restrict__ sid_s,
    float* __restrict__ out)
{
    __shared__ __align__(16) __bf16 Glds[128 * 128];   // 32 KB (one species)

    const int spec = blockIdx.x & 3;
    {
        const int4* src = (const int4*)(gfrag + (size_t)spec * 16384);
        for (int f = threadIdx.x; f < 2048; f += BLOCK)
            ((int4*)Glds)[f] = src[f];
    }
    __syncthreads();

    int off = 0;
    if (spec > 0) off += counts[0];
    if (spec > 1) off += counts[1];
    if (spec > 2) off += counts[2];
    const int cnt = counts[spec];

    const int lane = threadIdx.x & 63;
    const int r = lane & 15, g = lane >> 4;
    const int wsp = ((int)blockIdx.x >> 2) * (BLOCK / 64) + (threadIdx.x >> 6);
    const int gs  = ((int)gridDim.x >> 2) * (BLOCK / 64);
    const int ntiles = (cnt + 15) / 16;
    if (wsp >= ntiles) return;

    // ---- prologue: tile wsp's fragments + sid (sequential reads) ----
    bool v;
    int sid;
    bf16x8 xn0, xn1, xn2, xn3;
    {
        int l0 = wsp * 16 + r;
        v = l0 < cnt;
        const __bf16* p = psrt + (size_t)(off + (v ? l0 : 0)) * KF + g * 8;
        xn0 = *(const bf16x8*)(p);
        xn1 = *(const bf16x8*)(p + 32);
        xn2 = *(const bf16x8*)(p + 64);
        xn3 = *(const bf16x8*)(p + 96);
        sid = v ? sid_s[off + l0] : 0;
    }

    for (int t = wsp; t < ntiles; t += gs) {
        const bf16x8 xc0 = xn0, xc1 = xn1, xc2 = xn2, xc3 = xn3;
        const bool  curV   = v;
        const int   curSid = sid;

        // ---- issue next tile's loads (in flight under compute) ----
        const int tn = t + gs;
        if (tn < ntiles) {
            int l = tn * 16 + r;
            v = l < cnt;
            const __bf16* p = psrt + (size_t)(off + (v ? l : 0)) * KF + g * 8;
            xn0 = *(const bf16x8*)(p);
            xn1 = *(const bf16x8*)(p + 32);
            xn2 = *(const bf16x8*)(p + 64);
            xn3 = *(const bf16x8*)(p + 96);
            sid = v ? sid_s[off + l] : 0;
        }

        // ---- compute: 8 ct-steps, single species ----
        const __bf16* gp = Glds + lane * 8;
        float es = 0.f;
        GSTEP(0, xc0)
        GSTEP(1, xc0)
        __builtin_amdgcn_sched_barrier(0);
        GSTEP(2, xc1)
        GSTEP(3, xc1)
        __builtin_amdgcn_sched_barrier(0);
        GSTEP(4, xc2)
        GSTEP(5, xc2)
        __builtin_amdgcn_sched_barrier(0);
        GSTEP(6, xc3)
        GSTEP(7, xc3)

        float u = curV ? es : 0.f;   // g-slice partial of atom r's energy

        // ---- emit ----
        const int s0 = __shfl(curSid, 0);
        const bool uni = __all(curSid == s0);
        if (uni) {
            float tot = u;
            tot += __shfl_xor(tot, 1);  tot += __shfl_xor(tot, 2);
            tot += __shfl_xor(tot, 4);  tot += __shfl_xor(tot, 8);
            tot += __shfl_xor(tot, 16); tot += __shfl_xor(tot, 32);
            if (lane == 0 && tot != 0.f) atomicAdd(&out[s0], tot);
        } else {
            u += __shfl_xor(u, 16);
            u += __shfl_xor(u, 32);
            if (g == 0 && curV) atomicAdd(&out[curSid], u);
        }
    }
}

// ---------------- slow-but-correct fallback (ws too small) ----------------

__global__ void k_fallback(const float* __restrict__ ps, const float* __restrict__ support,
                           const float* __restrict__ weights, const int* __restrict__ species,
                           const int* __restrict__ struct_ids, float* __restrict__ out, int n)
{
    int gw = (blockIdx.x * blockDim.x + threadIdx.x) >> 6;
    int lane = threadIdx.x & 63;
    int nw = (gridDim.x * blockDim.x) >> 6;
    for (int atom = gw; atom < n; atom += nw) {
        const float* row = ps + (size_t)atom * KF;
        float x0 = row[lane], x1 = row[lane + 64];
        float nsum = x0 * x0 + x1 * x1;
        for (int o = 32; o; o >>= 1) nsum += __shfl_xor(nsum, o);
        float iv2 = 1.0f / nsum;
        int s = species[atom];
        const float* sup = support + (size_t)s * NSUP * KF;
        const float* w = weights + (size_t)s * NSUP;
        float e = 0.f;
        for (int mm = 0; mm < 4; ++mm) {
            int m = lane + mm * 64;
            const float* srow = sup + (size_t)m * KF;
            float d = 0.f;
            for (int k = 0; k < KF; ++k) d += row[k] * srow[k];
            e += d * d * w[m];
        }
        for (int o = 32; o; o >>= 1) e += __shfl_xor(e, o);
        if (lane == 0) atomicAdd(&out[struct_ids[atom]], e * iv2);
    }
}

// ---------------- launch ----------------

extern "C" void kernel_launch(void* const* d_in, const int* in_sizes, int n_in,
                              void* d_out, int out_size, void* d_ws, size_t ws_size,
                              hipStream_t stream)
{
    const float* ps       = (const float*)d_in[0];
    const float* support  = (const float*)d_in[1];
    const float* weights  = (const float*)d_in[2];
    const int*   species  = (const int*)d_in[3];
    const int*   sids     = (const int*)d_in[4];
    float* out = (float*)d_out;
    const int n = in_sizes[0] / KF;
    const int npad = (n + 63) & ~63;

    hipMemsetAsync(d_out, 0, (size_t)out_size * sizeof(float), stream);

    // ws layout: [counts 4 | cursors 4 | pad..64B] [dest n] [sid_s npad] [gfrag 128KB] [psrt npad*128 bf16]
    size_t off_dest  = 64;
    size_t off_sids  = off_dest + (size_t)n * 4;
    size_t off_gfrag = (off_sids + (size_t)npad * 4 + 255) & ~(size_t)255;
    size_t off_psrt  = (off_gfrag + NSPEC * 32 * 1024 + 255) & ~(size_t)255;
    size_t need      = off_psrt + (size_t)npad * KF * sizeof(__bf16);
    if (ws_size < need) {
        k_fallback<<<2048, 256, 0, stream>>>(ps, support, weights, species, sids, out, n);
        return;
    }

    int*    ws      = (int*)d_ws;
    int*    counts  = ws;        // [0..3]
    int*    cursors = ws + 8;    // [8..11]
    int*    dest    = (int*)((char*)d_ws + off_dest);
    int*    sid_s   = (int*)((char*)d_ws + off_sids);
    __bf16* gfrag   = (__bf16*)((char*)d_ws + off_gfrag);
    __bf16* psrt    = (__bf16*)((char*)d_ws + off_psrt);

    hipMemsetAsync(ws, 0, 64, stream);
    k_count<<<512, 256, 0, stream>>>(species, n, counts);
    k_dest<<<(n + 255) / 256, 256, 0, stream>>>(species, n, counts, cursors, dest);
    k_buildG<<<(NSPEC * 8 * 4 * 64 + 255) / 256, 256, 0, stream>>>(support, weights, gfrag);
    k_permute<<<2048, BLOCK, 0, stream>>>(ps, dest, sids, psrt, sid_s, n);
    k_main<<<2048, BLOCK, 0, stream>>>(psrt, gfrag, counts, sid_s, out);
}